// Round 1
// baseline (6869.350 us; speedup 1.0000x reference)
//
#include <hip/hip_runtime.h>
#include <hip/hip_fp16.h>

#define LDIM 200
#define BDIM 512
#define IDIM 512
#define HDIM 512
#define GDIM 1536  // 3*H

// ---------------------------------------------------------------------------
// K0: pack w_hh (f32 [1536][512]) -> wp (u32 [256][1536]),
//     wp[kp][c] = half2( w_hh[c][2kp], w_hh[c][2kp+1] )
// ---------------------------------------------------------------------------
__global__ __launch_bounds__(256) void k_pack_whh(
    const float* __restrict__ whh, unsigned int* __restrict__ wp)
{
    int idx = blockIdx.x * 256 + threadIdx.x;
    if (idx >= 256 * GDIM) return;
    int kp = idx / GDIM;
    int c  = idx - kp * GDIM;
    float a = whh[(size_t)c * HDIM + 2 * kp];
    float b = whh[(size_t)c * HDIM + 2 * kp + 1];
    __half2 h2 = __floats2half2_rn(a, b);
    union { __half2 h; unsigned int u; } cv;
    cv.h = h2;
    wp[idx] = cv.u;
}

// ---------------------------------------------------------------------------
// K1: gx[m][n] = sum_k x[b][l][k] * w_ih[n][k] + b_ih[n],  m = l*512 + b
//     stored as f16.  Tiles 64x64, BK=16, 256 threads, 4x4 per thread.
//     LDS tiles k-major: As[k][m], Bs[k][n] -> float4 reads, conflict-free.
// ---------------------------------------------------------------------------
__global__ __launch_bounds__(256) void k_gemm_gx(
    const float* __restrict__ x, const float* __restrict__ wih,
    const float* __restrict__ bih, __half* __restrict__ gx)
{
    const int bn = blockIdx.x * 64;   // over GDIM (24 tiles)
    const int bm = blockIdx.y * 64;   // over M = L*B (1600 tiles)
    __shared__ float As[16][64];
    __shared__ float Bs[16][64];
    const int t    = threadIdx.x;
    const int tx   = t & 15;          // output col quad
    const int ty   = t >> 4;          // output row quad
    const int srow = t >> 2;          // staging row (0..63)
    const int skq  = (t & 3) << 2;    // staging k offset (0,4,8,12)

    const int mA = bm + srow;
    const int lA = mA >> 9;
    const int bA = mA & 511;
    const float* aptr = x   + ((size_t)bA * LDIM + lA) * IDIM + skq;
    const float* bptr = wih + (size_t)(bn + srow) * IDIM + skq;

    float acc[4][4] = {};
    for (int k0 = 0; k0 < IDIM; k0 += 16) {
        const float4 a4 = *reinterpret_cast<const float4*>(aptr + k0);
        const float4 b4 = *reinterpret_cast<const float4*>(bptr + k0);
        __syncthreads();
        As[skq + 0][srow] = a4.x; As[skq + 1][srow] = a4.y;
        As[skq + 2][srow] = a4.z; As[skq + 3][srow] = a4.w;
        Bs[skq + 0][srow] = b4.x; Bs[skq + 1][srow] = b4.y;
        Bs[skq + 2][srow] = b4.z; Bs[skq + 3][srow] = b4.w;
        __syncthreads();
        #pragma unroll
        for (int kk = 0; kk < 16; ++kk) {
            const float4 a4v = *reinterpret_cast<const float4*>(&As[kk][ty << 2]);
            const float4 b4v = *reinterpret_cast<const float4*>(&Bs[kk][tx << 2]);
            const float avr[4] = {a4v.x, a4v.y, a4v.z, a4v.w};
            const float bvr[4] = {b4v.x, b4v.y, b4v.z, b4v.w};
            #pragma unroll
            for (int i = 0; i < 4; ++i)
                #pragma unroll
                for (int j = 0; j < 4; ++j)
                    acc[i][j] = fmaf(avr[i], bvr[j], acc[i][j]);
        }
    }

    const float4 bias = *reinterpret_cast<const float4*>(&bih[bn + (tx << 2)]);
    const float br[4] = {bias.x, bias.y, bias.z, bias.w};
    #pragma unroll
    for (int i = 0; i < 4; ++i) {
        const int m = bm + (ty << 2) + i;
        float v[4];
        #pragma unroll
        for (int j = 0; j < 4; ++j) v[j] = acc[i][j] + br[j];
        union { __half2 h; unsigned int u; } c01, c23;
        c01.h = __floats2half2_rn(v[0], v[1]);
        c23.h = __floats2half2_rn(v[2], v[3]);
        uint2 st; st.x = c01.u; st.y = c23.u;
        *reinterpret_cast<uint2*>(&gx[(size_t)m * GDIM + bn + (tx << 2)]) = st;
    }
}

// ---------------------------------------------------------------------------
// K2: recurrence. 256 blocks x 2 batch rows, 512 threads.
//     h[2][512] and gh[2][1536] live in LDS.  Thread t owns gh columns
//     3t..3t+2 for the dot phase (coalesced uint3 weight loads) and h
//     column t (gates r/z/n = t, t+512, t+1024) for the update phase.
// ---------------------------------------------------------------------------
__global__ __launch_bounds__(512) void k_recur(
    const __half* __restrict__ gx, const float* __restrict__ att,
    const float* __restrict__ h0, const unsigned int* __restrict__ wp,
    const float* __restrict__ bhh, float* __restrict__ out,
    float* __restrict__ hx)
{
    const int b0 = blockIdx.x << 1;
    const int t  = threadIdx.x;
    __shared__ float hsh[2][HDIM];
    __shared__ float ghs[2][GDIM];

    hsh[0][t] = h0[(size_t)b0 * HDIM + t];
    hsh[1][t] = h0[(size_t)(b0 + 1) * HDIM + t];
    const float bh0 = bhh[3 * t + 0];
    const float bh1 = bhh[3 * t + 1];
    const float bh2 = bhh[3 * t + 2];
    __syncthreads();

    for (int l = 0; l < LDIM; ++l) {
        // ---- phase 1: gh = h @ w_hh^T for this block's 2 rows ----
        float a00 = 0.f, a01 = 0.f, a02 = 0.f;
        float a10 = 0.f, a11 = 0.f, a12 = 0.f;
        const unsigned int* wr = wp + 3 * t;
        #pragma unroll 8
        for (int kp = 0; kp < 256; ++kp) {
            const uint3 w3 = *reinterpret_cast<const uint3*>(wr);
            wr += GDIM;
            const float2 hp0 = *reinterpret_cast<const float2*>(&hsh[0][kp << 1]);
            const float2 hp1 = *reinterpret_cast<const float2*>(&hsh[1][kp << 1]);
            const float2 f0 = __half22float2(*reinterpret_cast<const __half2*>(&w3.x));
            const float2 f1 = __half22float2(*reinterpret_cast<const __half2*>(&w3.y));
            const float2 f2 = __half22float2(*reinterpret_cast<const __half2*>(&w3.z));
            a00 = fmaf(hp0.y, f0.y, fmaf(hp0.x, f0.x, a00));
            a01 = fmaf(hp0.y, f1.y, fmaf(hp0.x, f1.x, a01));
            a02 = fmaf(hp0.y, f2.y, fmaf(hp0.x, f2.x, a02));
            a10 = fmaf(hp1.y, f0.y, fmaf(hp1.x, f0.x, a10));
            a11 = fmaf(hp1.y, f1.y, fmaf(hp1.x, f1.x, a11));
            a12 = fmaf(hp1.y, f2.y, fmaf(hp1.x, f2.x, a12));
        }
        ghs[0][3 * t + 0] = a00 + bh0;
        ghs[0][3 * t + 1] = a01 + bh1;
        ghs[0][3 * t + 2] = a02 + bh2;
        ghs[1][3 * t + 0] = a10 + bh0;
        ghs[1][3 * t + 1] = a11 + bh1;
        ghs[1][3 * t + 2] = a12 + bh2;
        __syncthreads();

        // ---- phase 2: gates + h update; thread t owns h column t ----
        #pragma unroll
        for (int r = 0; r < 2; ++r) {
            const int b = b0 + r;
            const __half* gxr = gx + ((size_t)l * BDIM + b) * GDIM;
            const float xr = __half2float(gxr[t]);
            const float xz = __half2float(gxr[t + 512]);
            const float xn = __half2float(gxr[t + 1024]);
            const float hrv = ghs[r][t];
            const float hzv = ghs[r][t + 512];
            const float hnv = ghs[r][t + 1024];
            const float h   = hsh[r][t];
            const float rg = 1.f / (1.f + __expf(-(xr + hrv)));
            const float zg = 1.f / (1.f + __expf(-(xz + hzv)));
            const float ng = tanhf(xn + rg * hnv);
            const float ho = (1.f - zg) * ng + zg * h;
            const float w  = att[(size_t)l * BDIM + b];
            const float hnew = (1.f - w) * h + w * ho;
            hsh[r][t] = hnew;
            out[((size_t)b * LDIM + l) * HDIM + t] = hnew;
        }
        __syncthreads();
    }

    hx[(size_t)b0 * HDIM + t]       = hsh[0][t];
    hx[(size_t)(b0 + 1) * HDIM + t] = hsh[1][t];
}

// ---------------------------------------------------------------------------
extern "C" void kernel_launch(void* const* d_in, const int* in_sizes, int n_in,
                              void* d_out, int out_size, void* d_ws, size_t ws_size,
                              hipStream_t stream)
{
    const float* x   = (const float*)d_in[0];
    const float* att = (const float*)d_in[1];
    const float* h0  = (const float*)d_in[2];
    const float* wih = (const float*)d_in[3];
    const float* whh = (const float*)d_in[4];
    const float* bih = (const float*)d_in[5];
    const float* bhh = (const float*)d_in[6];

    float* out = (float*)d_out;
    float* hx  = out + (size_t)BDIM * LDIM * HDIM;

    // workspace layout: [0, 1.5MB) packed w_hh ; [2MB, 2MB+315MB) gx (f16)
    unsigned int* wp = (unsigned int*)d_ws;
    __half* gx = (__half*)((char*)d_ws + ((size_t)2 << 20));

    k_pack_whh<<<(256 * GDIM + 255) / 256, 256, 0, stream>>>(whh, wp);
    k_gemm_gx<<<dim3(GDIM / 64, (LDIM * BDIM) / 64), 256, 0, stream>>>(x, wih, bih, gx);
    k_recur<<<BDIM / 2, 512, 0, stream>>>(gx, att, h0, wp, bhh, out, hx);
}